// Round 5
// baseline (248.430 us; speedup 1.0000x reference)
//
#include <hip/hip_runtime.h>
#include <hip/hip_bf16.h>
#include <stdint.h>

#define TB 8
#define TC 256
#define TH 120
#define TW 120
#define THW 14400
#define TOC 256
#define PH 122
#define PW 122

typedef short bf16x8 __attribute__((ext_vector_type(8)));
typedef float f32x4 __attribute__((ext_vector_type(4)));

// ---- workspace layout (bytes) ----
#define OUTP_BYTES ((size_t)TB * PH * PW * TC * 2)
#define YP_OFF     OUTP_BYTES
#define DK_OFF     (YP_OFF + (size_t)TB * TC * 9 * 4)
#define WP_OFF     (DK_OFF + (size_t)TB * TC * 9 * 4)

__global__ void zero_halo_kernel(char* __restrict__ outP) {
    int i = blockIdx.x * 256 + threadIdx.x;
    int pos_idx = i >> 5, part = i & 31;
    int b = pos_idx / 484; int k = pos_idx - b * 484;
    int h, w;
    if (k < 122)      { h = 0;   w = k; }
    else if (k < 244) { h = 121; w = k - 122; }
    else { int m = k - 244; h = 1 + (m >> 1); w = (m & 1) ? 121 : 0; }
    size_t pos = ((size_t)b * PH + h) * PW + w;
    uint4 z; z.x = 0u; z.y = 0u; z.z = 0u; z.w = 0u;
    *(uint4*)(outP + pos * 512 + part * 16) = z;
}

__global__ __launch_bounds__(128) void pool_kernel(const float* __restrict__ y,
                                                   float* __restrict__ yp) {
    int bc = blockIdx.x, t = threadIdx.x;
    __shared__ float pr[120][4];
    __shared__ float p2[9][8];
    const float* src = y + (size_t)bc * THW;
    if (t < 120) {
        const float4* row = (const float4*)(src + t * TW);
        float s0 = 0.f, s1 = 0.f, s2 = 0.f;
        #pragma unroll
        for (int j = 0; j < 10; ++j)  { float4 v = row[j]; s0 += (v.x + v.y) + (v.z + v.w); }
        #pragma unroll
        for (int j = 10; j < 20; ++j) { float4 v = row[j]; s1 += (v.x + v.y) + (v.z + v.w); }
        #pragma unroll
        for (int j = 20; j < 30; ++j) { float4 v = row[j]; s2 += (v.x + v.y) + (v.z + v.w); }
        pr[t][0] = s0; pr[t][1] = s1; pr[t][2] = s2;
    }
    __syncthreads();
    if (t < 72) {
        int bin = t >> 3, ch = t & 7;
        int bh = bin / 3, bw = bin - bh * 3;
        float a = 0.f;
        #pragma unroll
        for (int r = 0; r < 5; ++r) a += pr[bh * 40 + ch * 5 + r][bw];
        p2[bin][ch] = a;
    }
    __syncthreads();
    if (t < 9) {
        float a = 0.f;
        #pragma unroll
        for (int j = 0; j < 8; ++j) a += p2[t][j];
        yp[bc * 9 + t] = a * (1.f / 1600.f);
    }
}

__global__ void gen_kernel(const float* __restrict__ yp, const float* __restrict__ gen_w,
                           const float* __restrict__ gen_b, float* __restrict__ dk) {
    int b = blockIdx.x, t = threadIdx.x;
    __shared__ float yps[TC * 9];
    for (int i = t; i < TC * 9; i += 256) yps[i] = yp[b * TC * 9 + i];
    __syncthreads();
    float acc[9];
    float bias = gen_b[t];
    #pragma unroll
    for (int j = 0; j < 9; ++j) acc[j] = bias;
    for (int c = 0; c < TC; ++c) {
        float w = gen_w[t * TC + c];
        #pragma unroll
        for (int j = 0; j < 9; ++j) acc[j] += w * yps[c * 9 + j];
    }
    #pragma unroll
    for (int j = 0; j < 9; ++j) dk[(b * TC + t) * 9 + j] = acc[j];
}

__global__ __launch_bounds__(1024) void dw_kernel(const float* __restrict__ x,
        const float* __restrict__ dk, __hip_bfloat16* __restrict__ outP) {
    int bid = blockIdx.x;
    int hs = bid & 7;
    int cc = (bid >> 3) & 7;
    int b  = bid >> 6;
    int t = threadIdx.x;
    int c  = t >> 5;
    int wq = t & 31;
    bool active = wq < 30;
    int w0 = wq * 4;
    int cg = cc * 32 + c;
    const float* xp = x + (size_t)(b * TC + cg) * THW;
    const float* dkp = dk + (size_t)(b * TC + cg) * 9;
    float k0[3], k1[3], k2[3];
    #pragma unroll
    for (int j = 0; j < 3; ++j) { k0[j] = dkp[j]; k1[j] = dkp[3 + j]; k2[j] = dkp[6 + j]; }

    __shared__ __align__(16) __hip_bfloat16 stage[2][32][124];

    int h0 = hs * 15;
    float A[6], B[6], C[6];
    auto loadrow = [&](int hh, float* V) {
        if (hh < 0 || hh >= TH) {
            #pragma unroll
            for (int j = 0; j < 6; ++j) V[j] = 0.f;
            return;
        }
        const float* row = xp + hh * TW;
        float4 v = *(const float4*)(row + w0);
        V[1] = v.x; V[2] = v.y; V[3] = v.z; V[4] = v.w;
        V[0] = (wq > 0)  ? row[w0 - 1] : 0.f;
        V[5] = (wq < 29) ? row[w0 + 4] : 0.f;
    };
    if (active) { loadrow(h0 - 1, A); loadrow(h0, B); }

    for (int r = 0; r < 15; ++r) {
        int h = h0 + r;
        if (active) {
            loadrow(h + 1, C);
            ushort4 pk;
            #pragma unroll
            for (int i = 0; i < 4; ++i) {
                float o = A[i] * k0[0] + A[i + 1] * k0[1] + A[i + 2] * k0[2]
                        + B[i] * k1[0] + B[i + 1] * k1[1] + B[i + 2] * k1[2]
                        + C[i] * k2[0] + C[i + 1] * k2[1] + C[i + 2] * k2[2];
                __hip_bfloat16 hb = __float2bfloat16(o);
                ushort u = *(ushort*)&hb;
                if (i == 0) pk.x = u; else if (i == 1) pk.y = u;
                else if (i == 2) pk.z = u; else pk.w = u;
            }
            *(ushort4*)&stage[r & 1][c][w0] = pk;
            #pragma unroll
            for (int j = 0; j < 6; ++j) { A[j] = B[j]; B[j] = C[j]; }
        }
        __syncthreads();
        if (t < 480) {
            int w = t >> 2, part = t & 3;
            ushort vals[8];
            #pragma unroll
            for (int j = 0; j < 8; ++j) vals[j] = *(const ushort*)&stage[r & 1][part * 8 + j][w];
            uint4 o;
            o.x = (uint)vals[0] | ((uint)vals[1] << 16);
            o.y = (uint)vals[2] | ((uint)vals[3] << 16);
            o.z = (uint)vals[4] | ((uint)vals[5] << 16);
            o.w = (uint)vals[6] | ((uint)vals[7] << 16);
            size_t pos = ((size_t)b * PH + (h + 1)) * PW + (w + 1);
            *(uint4*)((char*)outP + pos * 512 + cc * 64 + part * 16) = o;
        }
    }
}

__global__ void wprep_kernel(const float* __restrict__ fuse_w, __hip_bfloat16* __restrict__ Wp) {
    int i = blockIdx.x * 256 + threadIdx.x;
    int ij = i >> 16;
    int oc = (i >> 8) & 255;
    int c  = i & 255;
    Wp[i] = __float2bfloat16(fuse_w[(oc * 256 + c) * 9 + ij]);
}

typedef const __attribute__((address_space(1))) char* gas_t;
typedef __attribute__((address_space(3))) char* las_t;
__device__ __forceinline__ void gload16(const char* g, char* l) {
    __builtin_amdgcn_global_load_lds((gas_t)g, (las_t)l, 16, 0, 0);
}
__device__ __forceinline__ void barrier_() {
    asm volatile("" ::: "memory");
    __builtin_amdgcn_s_barrier();
    asm volatile("" ::: "memory");
}

// 8-phase implicit GEMM, deep-staged variant.
// BM=256(m) x BN=256(oc) x BK=64.  Grid 450, 512 thr = 8 waves (2M x 4N).
// Group = 1 K-tile (4 phases, quadrants (0,0),(0,1),(1,0),(1,1)).
// Slot-free: B regions of buf fully ds_read by p2's trailing barrier, A by p3's.
// Stage tile T+2 into the SAME buf: B halves at p3, A halves at p4.
// One vmcnt(8) per group (after MMA(1,1)): drains tile T+1's 8 loads, issued
// 5-6 phases earlier (>= HBM miss latency).  Tail: G34 vmcnt(0), G35 none.
__global__ __launch_bounds__(512, 2) void gemm_kernel(
        const __hip_bfloat16* __restrict__ outP,
        const __hip_bfloat16* __restrict__ Wp,
        const float* __restrict__ fuse_b,
        float* __restrict__ res) {
    __shared__ __align__(16) char lds[2][65536];
    const int t = threadIdx.x;
    const int lane = t & 63;
    const int wv = t >> 6;
    const int wm = wv >> 2;      // m half (0..1)
    const int wn = wv & 3;       // oc quarter (0..3)

    // XCD swizzle, bijective for 450 = 8*56 + 2 (m204): q=56, r=2
    const int orig = blockIdx.x;
    const int xcd = orig & 7, lid = orig >> 3;
    const int bm = (xcd < 2 ? xcd * 57 : 114 + (xcd - 2) * 56) + lid;

    const char* gI = (const char*)outP;
    const char* gW = (const char*)Wp;

    // ---- read-side bases: addr = row*128 + (kbyte ^ ((row&7)<<4))
    const int sw  = (lane & 7) << 4;
    const int klo = (lane >> 4) << 4;
    const int rowA0 = wm * 128 + (lane & 15);
    const int aA_k0 = rowA0 * 128 + (klo ^ sw);
    const int aA_k1 = rowA0 * 128 + ((64 + klo) ^ sw);
    const int rowB0 = wn * 64 + (lane & 15);
    const int aB_k0 = 32768 + rowB0 * 128 + (klo ^ sw);
    const int aB_k1 = 32768 + rowB0 * 128 + ((64 + klo) ^ sw);

    // ---- staging: load r covers linear LDS bytes (r*512+t)*16 of a 16KB half
    const int srb = (((lane & 7) ^ (lane >> 3)) << 4);
    int srcA[2][2], srcB[2][2];
    #pragma unroll
    for (int h = 0; h < 2; ++h) {
        #pragma unroll
        for (int r = 0; r < 2; ++r) {
            int p = r * 64 + wv * 8 + (lane >> 3);
            int m = bm * 256 + h * 128 + p;
            int b = m / THW; int rr = m - b * THW;
            int hh = rr / TW; int w = rr - hh * TW;
            srcA[h][r] = (((b * PH + hh) * PW + w) << 9) + srb;
            srcB[h][r] = ((h * 128 + p) << 9) + srb;
        }
    }

    bf16x8 rA[8], rB[8];
    f32x4 acc[8][4];
    #pragma unroll
    for (int f = 0; f < 8; ++f) {
        #pragma unroll
        for (int g = 0; g < 4; ++g) { f32x4 z = {0.f,0.f,0.f,0.f}; acc[f][g] = z; }
    }

    auto OFFI = [&](int s) {
        int ij = s >> 2; int di = ij / 3, dj = ij - di * 3;
        return ((di * PW + dj) << 9) + ((s & 3) << 7);
    };
    auto OFFW = [&](int s) {
        return ((s >> 2) << 17) + ((s & 3) << 7);
    };
    auto STA = [&](int buf, int h, int offI) {
        char* base = &lds[buf][h * 16384 + t * 16];
        gload16(gI + srcA[h][0] + offI, base);
        gload16(gI + srcA[h][1] + offI, base + 8192);
    };
    auto STB = [&](int buf, int h, int offW) {
        char* base = &lds[buf][32768 + h * 16384 + t * 16];
        gload16(gW + srcB[h][0] + offW, base);
        gload16(gW + srcB[h][1] + offW, base + 8192);
    };

#define DS_A(BUF, MH) \
    { _Pragma("unroll") for (int f = 0; f < 4; ++f) { \
        rA[f*2+0] = *(const bf16x8*)(&lds[BUF][0] + aA_k0 + (MH)*8192 + f*2048); \
        rA[f*2+1] = *(const bf16x8*)(&lds[BUF][0] + aA_k1 + (MH)*8192 + f*2048); } }
#define DS_B(BUF, OH) \
    { _Pragma("unroll") for (int g = 0; g < 2; ++g) { \
        rB[(OH)*4+g*2+0] = *(const bf16x8*)(&lds[BUF][0] + aB_k0 + (OH)*4096 + g*2048); \
        rB[(OH)*4+g*2+1] = *(const bf16x8*)(&lds[BUF][0] + aB_k1 + (OH)*4096 + g*2048); } }
#define MMA(MH, OH) \
    { __builtin_amdgcn_s_setprio(1); \
      _Pragma("unroll") for (int kk = 0; kk < 2; ++kk) \
        _Pragma("unroll") for (int f = 0; f < 4; ++f) \
          _Pragma("unroll") for (int g = 0; g < 2; ++g) \
            acc[(MH)*4+f][(OH)*2+g] = __builtin_amdgcn_mfma_f32_16x16x32_bf16( \
                rB[(OH)*4+g*2+kk], rA[f*2+kk], acc[(MH)*4+f][(OH)*2+g], 0, 0, 0); \
      __builtin_amdgcn_s_setprio(0); }

    // GROUP(buf, T): compute tile T from buf; stage tile T+2 into same buf
    // (B at p3 after B-free, A at p4 after A-free); waitMode: 0=vmcnt(8),
    // 1=vmcnt(0), 2=none.
    auto GROUP = [&](int buf, int stageT, int waitMode) {
        // p1
        DS_A(buf, 0); DS_B(buf, 0);
        barrier_(); MMA(0, 0); barrier_();
        // p2
        DS_B(buf, 1);
        barrier_(); MMA(0, 1); barrier_();
        // p3
        DS_A(buf, 1);
        if (stageT >= 0) { int oW = OFFW(stageT); STB(buf, 0, oW); STB(buf, 1, oW); }
        barrier_(); MMA(1, 0); barrier_();
        // p4
        if (stageT >= 0) { int oI = OFFI(stageT); STA(buf, 0, oI); STA(buf, 1, oI); }
        barrier_(); MMA(1, 1);
        if (waitMode == 0)      { asm volatile("s_waitcnt vmcnt(8)" ::: "memory"); }
        else if (waitMode == 1) { asm volatile("s_waitcnt vmcnt(0)" ::: "memory"); }
        barrier_();
    };

    // ---- prologue: stage tiles 0 and 1 fully; wait tile 0 (keep tile 1 in flight)
    {
        int oI0 = OFFI(0), oW0 = OFFW(0), oI1 = OFFI(1), oW1 = OFFW(1);
        STA(0, 0, oI0); STA(0, 1, oI0); STB(0, 0, oW0); STB(0, 1, oW0);
        STA(1, 0, oI1); STA(1, 1, oI1); STB(1, 0, oW1); STB(1, 1, oW1);
    }
    asm volatile("s_waitcnt vmcnt(8)" ::: "memory");
    barrier_();

    #pragma unroll 1
    for (int gg = 0; gg < 17; ++gg) {
        GROUP(0, 2 * gg + 2, 0);
        GROUP(1, 2 * gg + 3, 0);
    }
    GROUP(0, -1, 1);   // tile 34: drain tile 35's loads
    GROUP(1, -1, 2);   // tile 35
#undef DS_A
#undef DS_B
#undef MMA

    // ---- epilogue: col(lane&15)=m, row-group((lane>>4)*4+j)=oc (m89 layout)
    int baseM[8];
    #pragma unroll
    for (int f = 0; f < 8; ++f) {
        int m = bm * 256 + wm * 128 + f * 16 + (lane & 15);
        int b = m / THW; int rr = m - b * THW;
        baseM[f] = b * (TOC * THW) + rr;
    }
    const int oc0 = wn * 64 + ((lane >> 4) << 2);
    float bias[4][4];
    #pragma unroll
    for (int g = 0; g < 4; ++g) {
        #pragma unroll
        for (int j = 0; j < 4; ++j) bias[g][j] = fuse_b[oc0 + g * 16 + j];
    }
    #pragma unroll
    for (int g = 0; g < 4; ++g) {
        #pragma unroll
        for (int f = 0; f < 8; ++f) {
            #pragma unroll
            for (int j = 0; j < 4; ++j)
                res[baseM[f] + (oc0 + g * 16 + j) * THW] = acc[f][g][j] + bias[g][j];
        }
    }
}

extern "C" void kernel_launch(void* const* d_in, const int* in_sizes, int n_in,
                              void* d_out, int out_size, void* d_ws, size_t ws_size,
                              hipStream_t stream) {
    const float* x      = (const float*)d_in[0];
    const float* y      = (const float*)d_in[1];
    const float* gen_w  = (const float*)d_in[2];
    const float* gen_b  = (const float*)d_in[3];
    const float* fuse_w = (const float*)d_in[4];
    const float* fuse_b = (const float*)d_in[5];
    float* out = (float*)d_out;
    char* ws = (char*)d_ws;

    __hip_bfloat16* outP = (__hip_bfloat16*)(ws);
    float* yp = (float*)(ws + YP_OFF);
    float* dk = (float*)(ws + DK_OFF);
    __hip_bfloat16* Wp = (__hip_bfloat16*)(ws + WP_OFF);

    zero_halo_kernel<<<484, 256, 0, stream>>>((char*)outP);
    pool_kernel<<<TB * TC, 128, 0, stream>>>(y, yp);
    gen_kernel<<<TB, 256, 0, stream>>>(yp, gen_w, gen_b, dk);
    wprep_kernel<<<2304, 256, 0, stream>>>(fuse_w, Wp);
    dw_kernel<<<512, 1024, 0, stream>>>(x, dk, outP);
    gemm_kernel<<<450, 512, 0, stream>>>(outP, Wp, fuse_b, out);
}

// Round 6
// 223.942 us; speedup vs baseline: 1.1094x; 1.1094x over previous
//
#include <hip/hip_runtime.h>
#include <hip/hip_bf16.h>
#include <stdint.h>

#define TB 8
#define TC 256
#define TH 120
#define TW 120
#define THW 14400
#define TOC 256
#define PH 122
#define PW 122

typedef short bf16x8 __attribute__((ext_vector_type(8)));
typedef float f32x4 __attribute__((ext_vector_type(4)));

// ---- workspace layout (bytes) ----
#define OUTP_BYTES ((size_t)TB * PH * PW * TC * 2)
#define YP_OFF     OUTP_BYTES
#define DK_OFF     (YP_OFF + (size_t)TB * TC * 9 * 4)
#define WP_OFF     (DK_OFF + (size_t)TB * TC * 9 * 4)

__global__ void zero_halo_kernel(char* __restrict__ outP) {
    int i = blockIdx.x * 256 + threadIdx.x;
    int pos_idx = i >> 5, part = i & 31;
    int b = pos_idx / 484; int k = pos_idx - b * 484;
    int h, w;
    if (k < 122)      { h = 0;   w = k; }
    else if (k < 244) { h = 121; w = k - 122; }
    else { int m = k - 244; h = 1 + (m >> 1); w = (m & 1) ? 121 : 0; }
    size_t pos = ((size_t)b * PH + h) * PW + w;
    uint4 z; z.x = 0u; z.y = 0u; z.z = 0u; z.w = 0u;
    *(uint4*)(outP + pos * 512 + part * 16) = z;
}

__global__ __launch_bounds__(128) void pool_kernel(const float* __restrict__ y,
                                                   float* __restrict__ yp) {
    int bc = blockIdx.x, t = threadIdx.x;
    __shared__ float pr[120][4];
    __shared__ float p2[9][8];
    const float* src = y + (size_t)bc * THW;
    if (t < 120) {
        const float4* row = (const float4*)(src + t * TW);
        float s0 = 0.f, s1 = 0.f, s2 = 0.f;
        #pragma unroll
        for (int j = 0; j < 10; ++j)  { float4 v = row[j]; s0 += (v.x + v.y) + (v.z + v.w); }
        #pragma unroll
        for (int j = 10; j < 20; ++j) { float4 v = row[j]; s1 += (v.x + v.y) + (v.z + v.w); }
        #pragma unroll
        for (int j = 20; j < 30; ++j) { float4 v = row[j]; s2 += (v.x + v.y) + (v.z + v.w); }
        pr[t][0] = s0; pr[t][1] = s1; pr[t][2] = s2;
    }
    __syncthreads();
    if (t < 72) {
        int bin = t >> 3, ch = t & 7;
        int bh = bin / 3, bw = bin - bh * 3;
        float a = 0.f;
        #pragma unroll
        for (int r = 0; r < 5; ++r) a += pr[bh * 40 + ch * 5 + r][bw];
        p2[bin][ch] = a;
    }
    __syncthreads();
    if (t < 9) {
        float a = 0.f;
        #pragma unroll
        for (int j = 0; j < 8; ++j) a += p2[t][j];
        yp[bc * 9 + t] = a * (1.f / 1600.f);
    }
}

// gen split: 64 blocks = (b, ocg of 32 oc); thread = (cseg 0..7, ocl 0..31)
__global__ __launch_bounds__(256) void gen_kernel(const float* __restrict__ yp,
        const float* __restrict__ gen_w, const float* __restrict__ gen_b,
        float* __restrict__ dk) {
    int blk = blockIdx.x;
    int b = blk >> 3, ocg = blk & 7;
    int t = threadIdx.x;
    int ocl = t & 31, cseg = t >> 5;
    int oc = ocg * 32 + ocl;
    __shared__ float yps[TC * 9];
    for (int i = t; i < TC * 9; i += 256) yps[i] = yp[b * TC * 9 + i];
    __syncthreads();
    float acc[9];
    #pragma unroll
    for (int j = 0; j < 9; ++j) acc[j] = 0.f;
    const float* wrow = gen_w + (size_t)oc * TC + cseg * 32;
    for (int c = 0; c < 32; ++c) {
        float w = wrow[c];
        const float* yrow = &yps[(cseg * 32 + c) * 9];
        #pragma unroll
        for (int j = 0; j < 9; ++j) acc[j] += w * yrow[j];
    }
    __shared__ float red[8][32][9];
    #pragma unroll
    for (int j = 0; j < 9; ++j) red[cseg][ocl][j] = acc[j];
    __syncthreads();
    for (int st = 4; st > 0; st >>= 1) {
        if (cseg < st) {
            #pragma unroll
            for (int j = 0; j < 9; ++j) red[cseg][ocl][j] += red[cseg + st][ocl][j];
        }
        __syncthreads();
    }
    if (cseg == 0) {
        float bias = gen_b[oc];
        #pragma unroll
        for (int j = 0; j < 9; ++j)
            dk[((size_t)b * TC + oc) * 9 + j] = red[0][ocl][j] + bias;
    }
}

// depthwise dynamic 3x3 -> channel-last padded bf16, pair-pipelined flush.
// Grid (b, cc, hs) = 512 blocks, 1024 threads; thread (c=t>>5, wq=t&31, wq<30).
// Rows processed in pairs; flush of pair p-1 overlaps compute of pair p.
__global__ __launch_bounds__(1024) void dw_kernel(const float* __restrict__ x,
        const float* __restrict__ dk, __hip_bfloat16* __restrict__ outP) {
    int bid = blockIdx.x;
    int hs = bid & 7;
    int cc = (bid >> 3) & 7;
    int b  = bid >> 6;
    int t = threadIdx.x;
    int c  = t >> 5;
    int wq = t & 31;
    bool active = wq < 30;
    int w0 = wq * 4;
    int cg = cc * 32 + c;
    const float* xp = x + (size_t)(b * TC + cg) * THW;
    const float* dkp = dk + (size_t)(b * TC + cg) * 9;
    float k0[3], k1[3], k2[3];
    #pragma unroll
    for (int j = 0; j < 3; ++j) { k0[j] = dkp[j]; k1[j] = dkp[3 + j]; k2[j] = dkp[6 + j]; }

    __shared__ __align__(16) __hip_bfloat16 stage[2][2][32][124];

    int h0 = hs * 15;
    float A[6], B[6], C[6];
    auto loadrow = [&](int hh, float* V) {
        if (hh < 0 || hh >= TH) {
            #pragma unroll
            for (int j = 0; j < 6; ++j) V[j] = 0.f;
            return;
        }
        const float* row = xp + hh * TW;
        float4 v = *(const float4*)(row + w0);
        V[1] = v.x; V[2] = v.y; V[3] = v.z; V[4] = v.w;
        V[0] = (wq > 0)  ? row[w0 - 1] : 0.f;
        V[5] = (wq < 29) ? row[w0 + 4] : 0.f;
    };
    auto comp = [&](int r, int par, int sub) {
        if (!active) return;
        loadrow(h0 + r + 1, C);
        ushort4 pk;
        #pragma unroll
        for (int i = 0; i < 4; ++i) {
            float o = A[i] * k0[0] + A[i + 1] * k0[1] + A[i + 2] * k0[2]
                    + B[i] * k1[0] + B[i + 1] * k1[1] + B[i + 2] * k1[2]
                    + C[i] * k2[0] + C[i + 1] * k2[1] + C[i + 2] * k2[2];
            __hip_bfloat16 hb = __float2bfloat16(o);
            ushort u = *(ushort*)&hb;
            if (i == 0) pk.x = u; else if (i == 1) pk.y = u;
            else if (i == 2) pk.z = u; else pk.w = u;
        }
        *(ushort4*)&stage[par][sub][c][w0] = pk;
        #pragma unroll
        for (int j = 0; j < 6; ++j) { A[j] = B[j]; B[j] = C[j]; }
    };
    auto flushrow = [&](int r, int par, int sub, int tt) {
        int w = tt >> 2, part = tt & 3;
        ushort vals[8];
        #pragma unroll
        for (int j = 0; j < 8; ++j) vals[j] = *(const ushort*)&stage[par][sub][part * 8 + j][w];
        uint4 o;
        o.x = (uint)vals[0] | ((uint)vals[1] << 16);
        o.y = (uint)vals[2] | ((uint)vals[3] << 16);
        o.z = (uint)vals[4] | ((uint)vals[5] << 16);
        o.w = (uint)vals[6] | ((uint)vals[7] << 16);
        size_t pos = ((size_t)b * PH + (h0 + r + 1)) * PW + (w + 1);
        *(uint4*)((char*)outP + pos * 512 + cc * 64 + part * 16) = o;
    };

    if (active) { loadrow(h0 - 1, A); loadrow(h0, B); }
    comp(0, 0, 0); comp(1, 0, 1);
    __syncthreads();
    #pragma unroll 1
    for (int p = 1; p < 8; ++p) {
        int r0 = 2 * p;
        comp(r0, p & 1, 0);
        if (r0 + 1 < 15) comp(r0 + 1, p & 1, 1);
        if (t < 960) {
            int fr = t >= 480 ? 1 : 0;
            int tt = t - fr * 480;
            flushrow(2 * (p - 1) + fr, (p - 1) & 1, fr, tt);
        }
        __syncthreads();
    }
    if (t < 480) flushrow(14, 1, 0, t);   // pair 7 = row 14 only
}

__global__ void wprep_kernel(const float* __restrict__ fuse_w, __hip_bfloat16* __restrict__ Wp) {
    int i = blockIdx.x * 256 + threadIdx.x;
    int ij = i >> 16;
    int oc = (i >> 8) & 255;
    int c  = i & 255;
    Wp[i] = __float2bfloat16(fuse_w[(oc * 256 + c) * 9 + ij]);
}

typedef const __attribute__((address_space(1))) char* gas_t;
typedef __attribute__((address_space(3))) char* las_t;
__device__ __forceinline__ void gload16(const char* g, char* l) {
    __builtin_amdgcn_global_load_lds((gas_t)g, (las_t)l, 16, 0, 0);
}

// Implicit GEMM (R3-proven): 128x128 tile, BK=64, 4 waves, global_load_lds w=16,
// pre-swizzled source + linear LDS + swizzled read, double-buffer, counted
// vmcnt(8), raw barriers, setprio, XCD swizzle (1800 % 8 == 0, bijective).
__global__ __launch_bounds__(256, 2) void gemm_kernel(
        const __hip_bfloat16* __restrict__ outP,
        const __hip_bfloat16* __restrict__ Wp,
        const float* __restrict__ fuse_b,
        float* __restrict__ res) {
    __shared__ __align__(16) char lds[2][32768];
    const int t = threadIdx.x;
    const int lane = t & 63;
    const int wv = t >> 6;
    const int wo = wv >> 1;      // oc half
    const int wm = wv & 1;       // m half

    const int bid0 = blockIdx.x;
    const int logical = (bid0 & 7) * 225 + (bid0 >> 3);
    const int bn = logical & 1;      // oc tile (0..1)
    const int bm = logical >> 1;     // m tile (0..899)

    const char* gI = (const char*)outP;
    const char* gW = (const char*)Wp;

    const int rbp = (((lane & 7) ^ (lane >> 3)) << 4);
    int srcI[4], srcW[4];
    #pragma unroll
    for (int q = 0; q < 4; ++q) {
        int p = (q * 4 + wv) * 8 + (lane >> 3);
        int m = bm * 128 + p;
        int b = m / THW; int r = m - b * THW;
        int h = r / TW;  int w = r - h * TW;
        srcI[q] = (((b * PH + h) * PW + w) << 9) + rbp;
        srcW[q] = ((bn * 128 + p) << 9) + rbp;
    }
    const int segBase = wv * 1024;

    int aWb[4], aWs[4], aIb[4], aIs[4];
    #pragma unroll
    for (int i = 0; i < 4; ++i) {
        int rw = wo * 64 + i * 16 + (lane & 15);
        aWb[i] = rw * 128; aWs[i] = (rw & 7) << 4;
        int ri = wm * 64 + i * 16 + (lane & 15);
        aIb[i] = ri * 128; aIs[i] = (ri & 7) << 4;
    }
    const int klo = (lane >> 4) << 4;

    f32x4 acc[4][4];
    #pragma unroll
    for (int i = 0; i < 4; ++i) {
        #pragma unroll
        for (int j = 0; j < 4; ++j) {
            f32x4 z = {0.f, 0.f, 0.f, 0.f};
            acc[i][j] = z;
        }
    }

    auto step_offs = [&](int s, int& offI, int& offW) {
        int ij = s >> 2;
        int c0b = (s & 3) << 7;
        int di = ij / 3, dj = ij - (ij / 3) * 3;
        offI = ((di * PW + dj) << 9) + c0b;
        offW = (ij << 17) + c0b;
    };
    auto STAGE = [&](int buf, int s) {
        int offI, offW; step_offs(s, offI, offW);
        char* LI = &lds[buf][0];
        char* LW = &lds[buf][16384];
        #pragma unroll
        for (int q = 0; q < 4; ++q) {
            gload16(gI + srcI[q] + offI, LI + segBase + q * 4096);
            gload16(gW + srcW[q] + offW, LW + segBase + q * 4096);
        }
    };
    auto COMPUTE = [&](int buf) {
        const char* LI = &lds[buf][0];
        const char* LW = &lds[buf][16384];
        #pragma unroll
        for (int kk = 0; kk < 2; ++kk) {
            int ck = kk * 64 + klo;
            bf16x8 wf[4], iff[4];
            #pragma unroll
            for (int i = 0; i < 4; ++i)
                wf[i] = *(const bf16x8*)(LW + aWb[i] + (ck ^ aWs[i]));
            #pragma unroll
            for (int i = 0; i < 4; ++i)
                iff[i] = *(const bf16x8*)(LI + aIb[i] + (ck ^ aIs[i]));
            __builtin_amdgcn_s_setprio(1);
            #pragma unroll
            for (int o = 0; o < 4; ++o) {
                #pragma unroll
                for (int mi = 0; mi < 4; ++mi)
                    acc[o][mi] = __builtin_amdgcn_mfma_f32_16x16x32_bf16(
                        wf[o], iff[mi], acc[o][mi], 0, 0, 0);
            }
            __builtin_amdgcn_s_setprio(0);
        }
    };

    STAGE(0, 0);
    #pragma unroll 1
    for (int s = 0; s < 35; ++s) {
        int cur = s & 1;
        STAGE(cur ^ 1, s + 1);
        asm volatile("s_waitcnt vmcnt(8)" ::: "memory");
        __builtin_amdgcn_s_barrier();
        asm volatile("" ::: "memory");
        COMPUTE(cur);
        asm volatile("" ::: "memory");
        __builtin_amdgcn_s_barrier();
        asm volatile("" ::: "memory");
    }
    asm volatile("s_waitcnt vmcnt(0)" ::: "memory");
    __builtin_amdgcn_s_barrier();
    asm volatile("" ::: "memory");
    COMPUTE(1);

    int baseM[4];
    #pragma unroll
    for (int mt = 0; mt < 4; ++mt) {
        int m = bm * 128 + wm * 64 + mt * 16 + (lane & 15);
        int b = m / THW; int r = m - b * THW;
        baseM[mt] = b * (TOC * THW) + r;
    }
    const int ocb0 = bn * 128 + wo * 64 + ((lane >> 4) << 2);
    float bias[4][4];
    #pragma unroll
    for (int o = 0; o < 4; ++o) {
        #pragma unroll
        for (int g = 0; g < 4; ++g)
            bias[o][g] = fuse_b[ocb0 + o * 16 + g];
    }
    #pragma unroll
    for (int o = 0; o < 4; ++o) {
        #pragma unroll
        for (int mt = 0; mt < 4; ++mt) {
            #pragma unroll
            for (int g = 0; g < 4; ++g)
                res[baseM[mt] + (ocb0 + o * 16 + g) * THW] = acc[o][mt][g] + bias[o][g];
        }
    }
}

extern "C" void kernel_launch(void* const* d_in, const int* in_sizes, int n_in,
                              void* d_out, int out_size, void* d_ws, size_t ws_size,
                              hipStream_t stream) {
    const float* x      = (const float*)d_in[0];
    const float* y      = (const float*)d_in[1];
    const float* gen_w  = (const float*)d_in[2];
    const float* gen_b  = (const float*)d_in[3];
    const float* fuse_w = (const float*)d_in[4];
    const float* fuse_b = (const float*)d_in[5];
    float* out = (float*)d_out;
    char* ws = (char*)d_ws;

    __hip_bfloat16* outP = (__hip_bfloat16*)(ws);
    float* yp = (float*)(ws + YP_OFF);
    float* dk = (float*)(ws + DK_OFF);
    __hip_bfloat16* Wp = (__hip_bfloat16*)(ws + WP_OFF);

    zero_halo_kernel<<<484, 256, 0, stream>>>((char*)outP);
    pool_kernel<<<TB * TC, 128, 0, stream>>>(y, yp);
    gen_kernel<<<64, 256, 0, stream>>>(yp, gen_w, gen_b, dk);
    wprep_kernel<<<2304, 256, 0, stream>>>(fuse_w, Wp);
    dw_kernel<<<512, 1024, 0, stream>>>(x, dk, outP);
    gemm_kernel<<<1800, 256, 0, stream>>>(outP, Wp, fuse_b, out);
}